// Round 2
// baseline (114.750 us; speedup 1.0000x reference)
//
#include <hip/hip_runtime.h>

// MLP: 64 × (Linear(5,5)+ReLU) then Linear(5,1), BATCH = 1048576 rows.
// fp32 VALU issue-bound. R10: pin layer weights in VGPRs via empty-asm.
//
// R9 post-mortem: VGPR_Count stayed 32, dur stayed 51 µs — source
// restructuring + sched_barrier changed NOTHING. 32 VGPRs cannot hold
// W(32)+h(20), so the pre-RA scheduler is sinking/rematerializing the
// weight ds_reads per-use (the 32-reg contortion), costing ~35-60 extra
// issue slots/layer/thread: achieved useful-FMA rate is 64 TF vs the
// 103 TF measured v_fma_f32 ceiling (62%), ideal mix predicts 83%.
// Note 32 vs 64 VGPRs is the SAME occupancy tier (8 waves/SIMD) — the
// contortion buys nothing; it's a scheduler heuristic, not a trade.
//
// Fix: a dataflow pin the scheduler cannot undo. After loading the 8
// float4 of layer weights, route all 32 scalars through an empty
// asm volatile("" : "+v"(...)). The asm outputs ARE the values consumed
// by the FMAs: the loads can no longer be sunk or rematerialized past
// this point, and "+v" forces arch-VGPR class. Empty string = zero
// runtime instructions (rule-#17 liveness pattern, NOT the R2-R7 copy
// islands). Peak pressure W(32)+h(20)+acc(5) ≈ 60 regs < 128 budget.
//
// Expected per layer per thread: 8 broadcast ds_read_b128 + 100 v_fma
// (bias as first fma's VOP3 addend) + 20 v_max = the scalar ideal.
// Tell: VGPR_Count must jump to ~56-72. If it stays 32, pin failed.

#define MLP_DEPTH 64
#define MLP_D 5
#define ROWS 4

// LDS layout: layer l at sw[l*32]: k<25 -> W[j*5+i] (k=j*5+i), 25..29 -> b[j],
// 30..31 pad. Then at sw[2048]: W_out[0..4], b_out, pad, pad. Total 2056.
#define LDS_N 2056

__global__ __launch_bounds__(256, 4) void MLP_89687507075104_kernel(
    const float* __restrict__ x,      // [n, 5]
    const float* __restrict__ Ws,     // [64, 5, 5]
    const float* __restrict__ bs,     // [64, 5]
    const float* __restrict__ W_out,  // [1, 5]
    const float* __restrict__ b_out,  // [1]
    float* __restrict__ out,          // [n]
    int n)
{
    __shared__ float sw[LDS_N];
    for (int idx = threadIdx.x; idx < LDS_N; idx += 256) {
        float v;
        if (idx < MLP_DEPTH * 32) {
            const int l = idx >> 5, k = idx & 31;
            v = (k < 25) ? Ws[l * 25 + k]
              : (k < 30) ? bs[l * MLP_D + (k - 25)]
              : 0.0f;
        } else {
            const int k = idx - MLP_DEPTH * 32;
            v = (k < MLP_D) ? W_out[k] : (k == MLP_D) ? b_out[0] : 0.0f;
        }
        sw[idx] = v;
    }
    __syncthreads();

    const int t = blockIdx.x * blockDim.x + threadIdx.x;
    const long row0 = (long)t * ROWS;
    if (row0 >= n) return;

    // rows row0..row0+3 = 20 contiguous floats (80 B, 16B-aligned).
    const float4* xp = reinterpret_cast<const float4*>(x + row0 * MLP_D);
    const float4 q0 = xp[0], q1 = xp[1], q2 = xp[2], q3 = xp[3], q4 = xp[4];
    float h[ROWS][MLP_D];
    h[0][0]=q0.x; h[0][1]=q0.y; h[0][2]=q0.z; h[0][3]=q0.w; h[0][4]=q1.x;
    h[1][0]=q1.y; h[1][1]=q1.z; h[1][2]=q1.w; h[1][3]=q2.x; h[1][4]=q2.y;
    h[2][0]=q2.z; h[2][1]=q2.w; h[2][2]=q3.x; h[2][3]=q3.y; h[2][4]=q3.z;
    h[3][0]=q3.w; h[3][1]=q4.x; h[3][2]=q4.y; h[3][3]=q4.z; h[3][4]=q4.w;

#pragma unroll 2
    for (int l = 0; l < MLP_DEPTH; ++l) {
        // 8× ds_read_b128, broadcast (all lanes same address), offsets are
        // immediates off one per-layer base -> no per-read address VALU.
        const float4* wq = reinterpret_cast<const float4*>(&sw[l * 32]);
        float W[32];
#pragma unroll
        for (int m = 0; m < 8; ++m) {
            const float4 c = wq[m];
            W[4*m+0] = c.x; W[4*m+1] = c.y; W[4*m+2] = c.z; W[4*m+3] = c.w;
        }
        // DATAFLOW PIN: the asm outputs are the values the FMAs consume.
        // The ds_reads can no longer be sunk/rematerialized per-use, and
        // "+v" forces arch-VGPR class. Empty string -> zero instructions.
        asm volatile("" : "+v"(W[0]),  "+v"(W[1]),  "+v"(W[2]),  "+v"(W[3]),
                          "+v"(W[4]),  "+v"(W[5]),  "+v"(W[6]),  "+v"(W[7]),
                          "+v"(W[8]),  "+v"(W[9]),  "+v"(W[10]), "+v"(W[11]),
                          "+v"(W[12]), "+v"(W[13]), "+v"(W[14]), "+v"(W[15]));
        asm volatile("" : "+v"(W[16]), "+v"(W[17]), "+v"(W[18]), "+v"(W[19]),
                          "+v"(W[20]), "+v"(W[21]), "+v"(W[22]), "+v"(W[23]),
                          "+v"(W[24]), "+v"(W[25]), "+v"(W[26]), "+v"(W[27]),
                          "+v"(W[28]), "+v"(W[29]), "+v"(W[30]), "+v"(W[31]));

        // Row-fused compute+ReLU: acc live range is one row (5 regs).
        // i-outer/j-inner => 5 independent FMA chains cover VALU latency.
#pragma unroll
        for (int r = 0; r < ROWS; ++r) {
            float acc[MLP_D];
#pragma unroll
            for (int j = 0; j < MLP_D; ++j)
                acc[j] = fmaf(h[r][0], W[j * MLP_D + 0], W[25 + j]);
#pragma unroll
            for (int i = 1; i < MLP_D; ++i)
#pragma unroll
                for (int j = 0; j < MLP_D; ++j)
                    acc[j] = fmaf(h[r][i], W[j * MLP_D + i], acc[j]);
#pragma unroll
            for (int j = 0; j < MLP_D; ++j)
                h[r][j] = fmaxf(acc[j], 0.0f);
        }
    }

    // Output layer: Linear(5,1).
    const float4* oq = reinterpret_cast<const float4*>(&sw[MLP_DEPTH * 32]);
    const float4 c0 = oq[0], c1 = oq[1];
    const float wo0 = c0.x, wo1 = c0.y, wo2 = c0.z, wo3 = c0.w;
    const float wo4 = c1.x, bo = c1.y;
    float4 ov;
    float o[ROWS];
#pragma unroll
    for (int r = 0; r < ROWS; ++r) {
        float acc = fmaf(h[r][0], wo0, bo);
        acc = fmaf(h[r][1], wo1, acc);
        acc = fmaf(h[r][2], wo2, acc);
        acc = fmaf(h[r][3], wo3, acc);
        acc = fmaf(h[r][4], wo4, acc);
        o[r] = acc;
    }
    ov.x = o[0]; ov.y = o[1]; ov.z = o[2]; ov.w = o[3];
    *reinterpret_cast<float4*>(out + row0) = ov;
}

extern "C" void kernel_launch(void* const* d_in, const int* in_sizes, int n_in,
                              void* d_out, int out_size, void* d_ws, size_t ws_size,
                              hipStream_t stream) {
    const float* x     = (const float*)d_in[0];
    const float* Ws    = (const float*)d_in[1];
    const float* bs    = (const float*)d_in[2];
    const float* W_out = (const float*)d_in[3];
    const float* b_out = (const float*)d_in[4];
    float* out = (float*)d_out;

    const int n = in_sizes[0] / MLP_D;  // batch rows (1048576)
    const int block = 256;
    const int threads_needed = (n + ROWS - 1) / ROWS;
    const int grid = (threads_needed + block - 1) / block;  // 1024
    MLP_89687507075104_kernel<<<grid, block, 0, stream>>>(
        x, Ws, bs, W_out, b_out, out, n);
}

// Round 3
// 111.697 us; speedup vs baseline: 1.0273x; 1.0273x over previous
//
#include <hip/hip_runtime.h>

// MLP: 64 × (Linear(5,5)+ReLU) then Linear(5,1), BATCH = 1048576 rows.
// fp32 VALU issue-bound. R11: ROWS 4 -> 8 (halve LDS reads per FLOP).
//
// R10 post-mortem: empty-asm pin "took" (VGPR 32->36) but COST 2 µs.
// Three different sources converge to ~51-53 µs. Revised theory: the
// missing ~34% vs the 103 TF v_fma ceiling may not be extra VALU at all.
// Per CU per layer, 16 waves × 8 broadcast ds_read_b128 = 128 DS instrs;
// at m134's ~12 cyc/b128 that is ~1536 cyc of LDS pipe vs ~960 cyc of
// VALU wall -> LDS return bus would be the bottleneck. VALUBusy's >100%
// readings (gfx94x fallback formula) mean "100%" may really be ~80%.
//
// Experiment separating the hypotheses: ROWS=8. Per layer per thread
// 200 fma + 40 max, still 8 ds_read_b128 -> DS per FLOP halves,
// per-layer waitcnt/loop overhead per FLOP halves, VALU per FLOP same.
// Pre-committed read: ~40-43 µs => LDS-bound confirmed; ~45-47 µs =>
// per-layer overhead; ~51 µs => per-FMA overhead (next: SGPR weights).
//
// Occupancy: 131072 threads = 2048 waves = 2 waves/SIMD. Each wave has
// 5+ independent FMA chains and ~480 VALU cyc/layer to self-hide LDS
// latency; launch_bounds(256,2) gives a 256-VGPR budget for
// W(32)+h(40)+acc(5)+misc ≈ 85. Layer loop unroll 2 (I$: ~4KB body).

#define MLP_DEPTH 64
#define MLP_D 5
#define ROWS 8

// LDS layout: layer l at sw[l*32]: k<25 -> W[j*5+i] (k=j*5+i), 25..29 -> b[j],
// 30..31 pad. Then at sw[2048]: W_out[0..4], b_out, pad, pad. Total 2056.
#define LDS_N 2056

__global__ __launch_bounds__(256, 2) void MLP_89687507075104_kernel(
    const float* __restrict__ x,      // [n, 5]
    const float* __restrict__ Ws,     // [64, 5, 5]
    const float* __restrict__ bs,     // [64, 5]
    const float* __restrict__ W_out,  // [1, 5]
    const float* __restrict__ b_out,  // [1]
    float* __restrict__ out,          // [n]
    int n)
{
    __shared__ float sw[LDS_N];
    for (int idx = threadIdx.x; idx < LDS_N; idx += 256) {
        float v;
        if (idx < MLP_DEPTH * 32) {
            const int l = idx >> 5, k = idx & 31;
            v = (k < 25) ? Ws[l * 25 + k]
              : (k < 30) ? bs[l * MLP_D + (k - 25)]
              : 0.0f;
        } else {
            const int k = idx - MLP_DEPTH * 32;
            v = (k < MLP_D) ? W_out[k] : (k == MLP_D) ? b_out[0] : 0.0f;
        }
        sw[idx] = v;
    }
    __syncthreads();

    const int t = blockIdx.x * blockDim.x + threadIdx.x;
    const long row0 = (long)t * ROWS;
    if (row0 >= n) return;

    // rows row0..row0+7 = 40 contiguous floats (160 B, 16B-aligned).
    const float4* xp = reinterpret_cast<const float4*>(x + row0 * MLP_D);
    float tmp[ROWS * MLP_D];
#pragma unroll
    for (int m = 0; m < (ROWS * MLP_D) / 4; ++m) {
        const float4 c = xp[m];
        tmp[4*m+0] = c.x; tmp[4*m+1] = c.y; tmp[4*m+2] = c.z; tmp[4*m+3] = c.w;
    }
    float h[ROWS][MLP_D];
#pragma unroll
    for (int r = 0; r < ROWS; ++r)
#pragma unroll
        for (int i = 0; i < MLP_D; ++i)
            h[r][i] = tmp[r * MLP_D + i];

#pragma unroll 2
    for (int l = 0; l < MLP_DEPTH; ++l) {
        // 8× ds_read_b128, broadcast (all lanes same address), offsets are
        // immediates off one per-layer base -> no per-read address VALU.
        const float4* wq = reinterpret_cast<const float4*>(&sw[l * 32]);
        float W[32];
#pragma unroll
        for (int m = 0; m < 8; ++m) {
            const float4 c = wq[m];
            W[4*m+0] = c.x; W[4*m+1] = c.y; W[4*m+2] = c.z; W[4*m+3] = c.w;
        }

        // Row-fused compute+ReLU: acc live range is one row (5 regs).
        // i-outer/j-inner => 5 independent FMA chains cover VALU latency.
#pragma unroll
        for (int r = 0; r < ROWS; ++r) {
            float acc[MLP_D];
#pragma unroll
            for (int j = 0; j < MLP_D; ++j)
                acc[j] = fmaf(h[r][0], W[j * MLP_D + 0], W[25 + j]);
#pragma unroll
            for (int i = 1; i < MLP_D; ++i)
#pragma unroll
                for (int j = 0; j < MLP_D; ++j)
                    acc[j] = fmaf(h[r][i], W[j * MLP_D + i], acc[j]);
#pragma unroll
            for (int j = 0; j < MLP_D; ++j)
                h[r][j] = fmaxf(acc[j], 0.0f);
        }
    }

    // Output layer: Linear(5,1).
    const float4* oq = reinterpret_cast<const float4*>(&sw[MLP_DEPTH * 32]);
    const float4 c0 = oq[0], c1 = oq[1];
    const float wo0 = c0.x, wo1 = c0.y, wo2 = c0.z, wo3 = c0.w;
    const float wo4 = c1.x, bo = c1.y;
    float o[ROWS];
#pragma unroll
    for (int r = 0; r < ROWS; ++r) {
        float acc = fmaf(h[r][0], wo0, bo);
        acc = fmaf(h[r][1], wo1, acc);
        acc = fmaf(h[r][2], wo2, acc);
        acc = fmaf(h[r][3], wo3, acc);
        acc = fmaf(h[r][4], wo4, acc);
        o[r] = acc;
    }
    float4 ov0, ov1;
    ov0.x = o[0]; ov0.y = o[1]; ov0.z = o[2]; ov0.w = o[3];
    ov1.x = o[4]; ov1.y = o[5]; ov1.z = o[6]; ov1.w = o[7];
    float4* op = reinterpret_cast<float4*>(out + row0);
    op[0] = ov0;
    op[1] = ov1;
}

extern "C" void kernel_launch(void* const* d_in, const int* in_sizes, int n_in,
                              void* d_out, int out_size, void* d_ws, size_t ws_size,
                              hipStream_t stream) {
    const float* x     = (const float*)d_in[0];
    const float* Ws    = (const float*)d_in[1];
    const float* bs    = (const float*)d_in[2];
    const float* W_out = (const float*)d_in[3];
    const float* b_out = (const float*)d_in[4];
    float* out = (float*)d_out;

    const int n = in_sizes[0] / MLP_D;  // batch rows (1048576)
    const int block = 256;
    const int threads_needed = (n + ROWS - 1) / ROWS;
    const int grid = (threads_needed + block - 1) / block;  // 512
    MLP_89687507075104_kernel<<<grid, block, 0, stream>>>(
        x, Ws, bs, W_out, b_out, out, n);
}